// Round 1
// baseline (1081.322 us; speedup 1.0000x reference)
//
#include <hip/hip_runtime.h>
#include <stdint.h>

#define DIM 256
#define NEG_SLOPE 0.01f

// ---------------- utility kernels ----------------

__global__ __launch_bounds__(256) void zero_i32_kernel(int* __restrict__ p, int n) {
    int i = blockIdx.x * blockDim.x + threadIdx.x;
    int stride = gridDim.x * blockDim.x;
    for (; i < n; i += stride) p[i] = 0;
}

__global__ __launch_bounds__(256) void zero_f32_kernel(float* __restrict__ p, long long n) {
    long long i = (long long)blockIdx.x * blockDim.x + threadIdx.x;
    long long stride = (long long)gridDim.x * blockDim.x;
    for (; i < n; i += stride) p[i] = 0.0f;
}

// ---------------- GEMM: h = x @ W^T + b ----------------
// x: [M, 256], W: [256, 256] row-major (h[n,j] = sum_k x[n,k]*W[j,k] + b[j])
// 64x64 tile per 256-thread block, BK=16, 4x4 micro-tile per thread.
// LDS stored K-major (As[k][row]) so the inner loop does float4 LDS reads.

#define BM 64
#define BN 64
#define BK 16
#define LDP 68   // padded row length (floats); 68*4 bytes keeps 16B alignment

__global__ __launch_bounds__(256) void gemm_xwT_kernel(
        const float* __restrict__ x, const float* __restrict__ W,
        const float* __restrict__ bias, float* __restrict__ h, int M) {
    __shared__ float As[BK][LDP];   // As[k][r] = x[row0+r][kk+k]
    __shared__ float Bs[BK][LDP];   // Bs[k][c] = W[col0+c][kk+k]

    const int tid  = threadIdx.x;
    const int row0 = blockIdx.x * BM;
    const int col0 = blockIdx.y * BN;
    const int ty = tid >> 4;        // 0..15
    const int tx = tid & 15;        // 0..15
    const int lr = tid >> 2;        // 0..63  (row/col being loaded)
    const int lk = (tid & 3) * 4;   // 0,4,8,12

    float acc[4][4];
#pragma unroll
    for (int i = 0; i < 4; ++i)
#pragma unroll
        for (int j = 0; j < 4; ++j) acc[i][j] = 0.0f;

    for (int kk = 0; kk < DIM; kk += BK) {
        // load A tile (guard M tail)
        float4 av = make_float4(0.f, 0.f, 0.f, 0.f);
        if (row0 + lr < M)
            av = *(const float4*)(&x[(size_t)(row0 + lr) * DIM + kk + lk]);
        As[lk + 0][lr] = av.x; As[lk + 1][lr] = av.y;
        As[lk + 2][lr] = av.z; As[lk + 3][lr] = av.w;
        // load B tile (W rows are the output cols; always in range)
        float4 bv = *(const float4*)(&W[(size_t)(col0 + lr) * DIM + kk + lk]);
        Bs[lk + 0][lr] = bv.x; Bs[lk + 1][lr] = bv.y;
        Bs[lk + 2][lr] = bv.z; Bs[lk + 3][lr] = bv.w;
        __syncthreads();

#pragma unroll
        for (int k = 0; k < BK; ++k) {
            float4 a = *(const float4*)(&As[k][ty * 4]);
            float4 b = *(const float4*)(&Bs[k][tx * 4]);
            acc[0][0] += a.x * b.x; acc[0][1] += a.x * b.y; acc[0][2] += a.x * b.z; acc[0][3] += a.x * b.w;
            acc[1][0] += a.y * b.x; acc[1][1] += a.y * b.y; acc[1][2] += a.y * b.z; acc[1][3] += a.y * b.w;
            acc[2][0] += a.z * b.x; acc[2][1] += a.z * b.y; acc[2][2] += a.z * b.z; acc[2][3] += a.z * b.w;
            acc[3][0] += a.w * b.x; acc[3][1] += a.w * b.y; acc[3][2] += a.w * b.z; acc[3][3] += a.w * b.w;
        }
        __syncthreads();
    }

    const float4 bvec = *(const float4*)(&bias[col0 + tx * 4]);
#pragma unroll
    for (int i = 0; i < 4; ++i) {
        int row = row0 + ty * 4 + i;
        if (row < M) {
            float4 o = make_float4(acc[i][0] + bvec.x, acc[i][1] + bvec.y,
                                   acc[i][2] + bvec.z, acc[i][3] + bvec.w);
            *(float4*)(&h[(size_t)row * DIM + col0 + tx * 4]) = o;
        }
    }
}

// ---------------- CSR build ----------------

__global__ __launch_bounds__(256) void hist_kernel(const int* __restrict__ rows,
                                                   int* __restrict__ cnt, int E) {
    int i = blockIdx.x * blockDim.x + threadIdx.x;
    int stride = gridDim.x * blockDim.x;
    for (; i < E; i += stride) atomicAdd(&cnt[rows[i]], 1);
}

__device__ inline int wave_incl_scan(int v) {
    const int lane = threadIdx.x & 63;
#pragma unroll
    for (int off = 1; off < 64; off <<= 1) {
        int t = __shfl_up(v, off, 64);
        if (lane >= off) v += t;
    }
    return v;
}

// single-block exclusive scan of cnt[0..n) -> offs, cursor (chunked, wave-scan based)
__global__ __launch_bounds__(1024) void scan_kernel(const int* __restrict__ cnt,
                                                    int* __restrict__ offs,
                                                    int* __restrict__ cursor, int n) {
    __shared__ int wsum[16];
    __shared__ int srun;
    const int tid = (int)threadIdx.x;
    const int lane = tid & 63;
    const int wid = tid >> 6;   // 0..15
    if (tid == 0) srun = 0;
    __syncthreads();

    for (int base = 0; base < n; base += 1024) {
        int i = base + tid;
        int v = (i < n) ? cnt[i] : 0;
        int incl = wave_incl_scan(v);
        if (lane == 63) wsum[wid] = incl;
        __syncthreads();
        if (wid == 0) {
            int s = (lane < 16) ? wsum[lane] : 0;
            s = wave_incl_scan(s);
            if (lane < 16) wsum[lane] = s;
        }
        __syncthreads();
        int waveoff = (wid == 0) ? 0 : wsum[wid - 1];
        if (i < n) {
            int o = srun + waveoff + incl - v;   // exclusive
            offs[i] = o;
            cursor[i] = o;
        }
        __syncthreads();                 // everyone done reading srun
        if (tid == 1023) srun += wsum[15];
        __syncthreads();
    }
}

__global__ __launch_bounds__(256) void scatter_kernel(
        const int* __restrict__ rows, const int* __restrict__ cols,
        const float* __restrict__ vals, int* __restrict__ cursor,
        uint2* __restrict__ sorted, int E) {
    int i = blockIdx.x * blockDim.x + threadIdx.x;
    int stride = gridDim.x * blockDim.x;
    for (; i < E; i += stride) {
        int r = rows[i];
        int pos = atomicAdd(&cursor[r], 1);
        sorted[pos] = make_uint2((unsigned)cols[i], __float_as_uint(vals[i]));
    }
}

// ---------------- aggregation: one wave per node ----------------
// acc[r,:] = sum_{e in row r} val_e * h[col_e, :]; leaky-relu fused; row written once.

__global__ __launch_bounds__(64) void agg_kernel(
        const float* __restrict__ h, const uint2* __restrict__ sorted,
        const int* __restrict__ offs, const int* __restrict__ cnt,
        float* __restrict__ out) {
    const int node = blockIdx.x;
    const int lane = threadIdx.x;       // 0..63, handles 4 consecutive floats
    const int beg = offs[node];
    const int end = beg + cnt[node];

    float4 acc0 = make_float4(0.f, 0.f, 0.f, 0.f);
    float4 acc1 = make_float4(0.f, 0.f, 0.f, 0.f);

    int j = beg;
    for (; j + 1 < end; j += 2) {
        uint2 cv0 = sorted[j];
        uint2 cv1 = sorted[j + 1];
        float v0 = __uint_as_float(cv0.y);
        float v1 = __uint_as_float(cv1.y);
        float4 h0 = *(const float4*)(&h[(size_t)cv0.x * DIM + lane * 4]);
        float4 h1 = *(const float4*)(&h[(size_t)cv1.x * DIM + lane * 4]);
        acc0.x += v0 * h0.x; acc0.y += v0 * h0.y; acc0.z += v0 * h0.z; acc0.w += v0 * h0.w;
        acc1.x += v1 * h1.x; acc1.y += v1 * h1.y; acc1.z += v1 * h1.z; acc1.w += v1 * h1.w;
    }
    if (j < end) {
        uint2 cv = sorted[j];
        float v = __uint_as_float(cv.y);
        float4 hv = *(const float4*)(&h[(size_t)cv.x * DIM + lane * 4]);
        acc0.x += v * hv.x; acc0.y += v * hv.y; acc0.z += v * hv.z; acc0.w += v * hv.w;
    }
    float4 a = make_float4(acc0.x + acc1.x, acc0.y + acc1.y,
                           acc0.z + acc1.z, acc0.w + acc1.w);
    a.x = (a.x >= 0.f) ? a.x : NEG_SLOPE * a.x;
    a.y = (a.y >= 0.f) ? a.y : NEG_SLOPE * a.y;
    a.z = (a.z >= 0.f) ? a.z : NEG_SLOPE * a.z;
    a.w = (a.w >= 0.f) ? a.w : NEG_SLOPE * a.w;
    *(float4*)(&out[(size_t)node * DIM + lane * 4]) = a;
}

// ---------------- fallback: atomic scatter (only if ws too small for CSR) ----------------

__global__ __launch_bounds__(64) void edge_atomic_kernel(
        const int* __restrict__ rows, const int* __restrict__ cols,
        const float* __restrict__ vals, const float* __restrict__ h,
        float* __restrict__ out, int E) {
    const int e = blockIdx.x;
    if (e >= E) return;
    const int lane = threadIdx.x;
    const int r = rows[e];
    const int c = cols[e];
    const float v = vals[e];
    float4 hv = *(const float4*)(&h[(size_t)c * DIM + lane * 4]);
    float* dst = &out[(size_t)r * DIM + lane * 4];
    atomicAdd(dst + 0, v * hv.x);
    atomicAdd(dst + 1, v * hv.y);
    atomicAdd(dst + 2, v * hv.z);
    atomicAdd(dst + 3, v * hv.w);
}

__global__ __launch_bounds__(256) void leaky_kernel(float* __restrict__ p, long long n) {
    long long i = (long long)blockIdx.x * blockDim.x + threadIdx.x;
    long long stride = (long long)gridDim.x * blockDim.x;
    for (; i < n; i += stride) {
        float v = p[i];
        p[i] = (v >= 0.f) ? v : NEG_SLOPE * v;
    }
}

// ---------------- launch ----------------

extern "C" void kernel_launch(void* const* d_in, const int* in_sizes, int n_in,
                              void* d_out, int out_size, void* d_ws, size_t ws_size,
                              hipStream_t stream) {
    const float* x    = (const float*)d_in[0];
    const int*   erow = (const int*)d_in[1];
    const int*   ecol = (const int*)d_in[2];
    const float* eval_ = (const float*)d_in[3];
    const float* Ww   = (const float*)d_in[4];
    const float* Wb   = (const float*)d_in[5];
    float* out = (float*)d_out;

    const int N = in_sizes[0] / DIM;
    const int E = in_sizes[1];

    // workspace layout
    char* p = (char*)d_ws;
    float* h = (float*)p;                       p += (size_t)N * DIM * sizeof(float);
    int* cnt = (int*)p;                         p += (size_t)N * sizeof(int);
    int* offs = (int*)p;                        p += (size_t)N * sizeof(int);
    int* cursor = (int*)p;                      p += (size_t)N * sizeof(int);
    uintptr_t up = ((uintptr_t)p + 15) & ~(uintptr_t)15;
    uint2* sorted = (uint2*)up;
    size_t need_full = (size_t)((char*)sorted - (char*)d_ws) + (size_t)E * sizeof(uint2);
    size_t need_h = (size_t)N * DIM * sizeof(float);

    // Phase 1: h = x @ W^T + b
    dim3 ggrid((N + BM - 1) / BM, DIM / BN);
    gemm_xwT_kernel<<<ggrid, 256, 0, stream>>>(x, Ww, Wb, h, N);

    if (ws_size >= need_full) {
        // Phase 2: CSR build
        zero_i32_kernel<<<256, 256, 0, stream>>>(cnt, N);
        hist_kernel<<<1024, 256, 0, stream>>>(erow, cnt, E);
        scan_kernel<<<1, 1024, 0, stream>>>(cnt, offs, cursor, N);
        scatter_kernel<<<2048, 256, 0, stream>>>(erow, ecol, eval_, cursor, sorted, E);
        // Phase 3: per-node aggregation + fused leaky-relu
        agg_kernel<<<N, 64, 0, stream>>>(h, sorted, offs, cnt, out);
    } else if (ws_size >= need_h) {
        // fallback: atomic scatter
        zero_f32_kernel<<<2048, 256, 0, stream>>>(out, (long long)N * DIM);
        edge_atomic_kernel<<<E, 64, 0, stream>>>(erow, ecol, eval_, h, out, E);
        leaky_kernel<<<2048, 256, 0, stream>>>(out, (long long)N * DIM);
    }
    // (if ws is smaller than h we cannot run; harness ws is expected to be larger)
}

// Round 3
// 971.705 us; speedup vs baseline: 1.1128x; 1.1128x over previous
//
#include <hip/hip_runtime.h>
#include <stdint.h>

#define DIM 256
#define NEG_SLOPE 0.01f

typedef float vfloat4 __attribute__((ext_vector_type(4)));

// ---------------- utility kernels ----------------

__global__ __launch_bounds__(256) void zero_i32_kernel(int* __restrict__ p, int n) {
    int i = blockIdx.x * blockDim.x + threadIdx.x;
    int stride = gridDim.x * blockDim.x;
    for (; i < n; i += stride) p[i] = 0;
}

__global__ __launch_bounds__(256) void zero_f32_kernel(float* __restrict__ p, long long n) {
    long long i = (long long)blockIdx.x * blockDim.x + threadIdx.x;
    long long stride = (long long)gridDim.x * blockDim.x;
    for (; i < n; i += stride) p[i] = 0.0f;
}

// ---------------- GEMM: h = x @ W^T + b ----------------
// 128x64 tile per 256-thread block, BK=16, 8x4 micro-tile per thread.

#define GBM 128
#define GBN 64
#define GBK 16
#define GLDA 132   // padded row (floats) for As[k][0..127]
#define GLDB 68    // padded row (floats) for Bs[k][0..63]

__global__ __launch_bounds__(256) void gemm_xwT_kernel(
        const float* __restrict__ x, const float* __restrict__ W,
        const float* __restrict__ bias, float* __restrict__ h, int M) {
    __shared__ float As[GBK][GLDA];   // As[k][r] = x[row0+r][kk+k]
    __shared__ float Bs[GBK][GLDB];   // Bs[k][c] = W[col0+c][kk+k]

    const int tid  = threadIdx.x;
    const int row0 = blockIdx.x * GBM;
    const int col0 = blockIdx.y * GBN;
    const int ty = tid >> 4;        // 0..15 -> output rows ty*8 .. ty*8+7
    const int tx = tid & 15;        // output cols tx*4 .. tx*4+3
    const int lr = tid >> 2;        // 0..63
    const int lk = (tid & 3) * 4;   // 0,4,8,12

    float acc[8][4];
#pragma unroll
    for (int i = 0; i < 8; ++i)
#pragma unroll
        for (int j = 0; j < 4; ++j) acc[i][j] = 0.0f;

    for (int kk = 0; kk < DIM; kk += GBK) {
#pragma unroll
        for (int i = 0; i < 2; ++i) {
            int row = row0 + lr + i * 64;
            float4 av = make_float4(0.f, 0.f, 0.f, 0.f);
            if (row < M)
                av = *(const float4*)(&x[(size_t)row * DIM + kk + lk]);
            As[lk + 0][lr + i * 64] = av.x; As[lk + 1][lr + i * 64] = av.y;
            As[lk + 2][lr + i * 64] = av.z; As[lk + 3][lr + i * 64] = av.w;
        }
        float4 bv = *(const float4*)(&W[(size_t)(col0 + lr) * DIM + kk + lk]);
        Bs[lk + 0][lr] = bv.x; Bs[lk + 1][lr] = bv.y;
        Bs[lk + 2][lr] = bv.z; Bs[lk + 3][lr] = bv.w;
        __syncthreads();

#pragma unroll
        for (int k = 0; k < GBK; ++k) {
            float4 a0 = *(const float4*)(&As[k][ty * 8]);
            float4 a1 = *(const float4*)(&As[k][ty * 8 + 4]);
            float4 b  = *(const float4*)(&Bs[k][tx * 4]);
            float ar[8] = {a0.x, a0.y, a0.z, a0.w, a1.x, a1.y, a1.z, a1.w};
            float br[4] = {b.x, b.y, b.z, b.w};
#pragma unroll
            for (int i = 0; i < 8; ++i)
#pragma unroll
                for (int j = 0; j < 4; ++j)
                    acc[i][j] += ar[i] * br[j];
        }
        __syncthreads();
    }

    const float4 bvec = *(const float4*)(&bias[col0 + tx * 4]);
#pragma unroll
    for (int i = 0; i < 8; ++i) {
        int row = row0 + ty * 8 + i;
        if (row < M) {
            float4 o = make_float4(acc[i][0] + bvec.x, acc[i][1] + bvec.y,
                                   acc[i][2] + bvec.z, acc[i][3] + bvec.w);
            *(float4*)(&h[(size_t)row * DIM + col0 + tx * 4]) = o;
        }
    }
}

// ---------------- CSR build ----------------

__global__ __launch_bounds__(256) void hist_kernel(const int* __restrict__ rows,
                                                   int* __restrict__ cnt, int E) {
    int i = blockIdx.x * blockDim.x + threadIdx.x;
    int stride = gridDim.x * blockDim.x;
    for (; i < E; i += stride) atomicAdd(&cnt[rows[i]], 1);
}

__device__ inline int wave_incl_scan(int v) {
    const int lane = threadIdx.x & 63;
#pragma unroll
    for (int off = 1; off < 64; off <<= 1) {
        int t = __shfl_up(v, off, 64);
        if (lane >= off) v += t;
    }
    return v;
}

// Multi-block exclusive scan: chunk sums -> 1-wave scan of partials -> final.
#define SCHUNK 2048   // 256 threads x 8 elements

__global__ __launch_bounds__(256) void chunk_sum_kernel(const int* __restrict__ cnt,
                                                        int* __restrict__ psum, int n) {
    __shared__ int wtot[4];
    const int tid = (int)threadIdx.x;
    const int lane = tid & 63, wid = tid >> 6;
    const int base = blockIdx.x * SCHUNK + tid * 8;
    int s = 0;
#pragma unroll
    for (int i = 0; i < 8; ++i) {
        int idx = base + i;
        if (idx < n) s += cnt[idx];
    }
#pragma unroll
    for (int off = 32; off; off >>= 1) s += __shfl_xor(s, off, 64);
    if (lane == 0) wtot[wid] = s;
    __syncthreads();
    if (tid == 0) psum[blockIdx.x] = wtot[0] + wtot[1] + wtot[2] + wtot[3];
}

__global__ __launch_bounds__(64) void scan_psum_kernel(int* __restrict__ psum, int nchunks) {
    const int lane = (int)threadIdx.x;
    int run = 0;
    for (int b = 0; b < nchunks; b += 64) {
        int i = b + lane;
        int v = (i < nchunks) ? psum[i] : 0;
        int incl = wave_incl_scan(v);
        if (i < nchunks) psum[i] = run + incl - v;  // exclusive
        run += __shfl(incl, 63, 64);
    }
}

__global__ __launch_bounds__(256) void scan_final_kernel(const int* __restrict__ cnt,
        const int* __restrict__ psum, int* __restrict__ offs,
        int* __restrict__ cursor, int n) {
    __shared__ int wtot[4];
    const int tid = (int)threadIdx.x;
    const int lane = tid & 63, wid = tid >> 6;
    const int base = blockIdx.x * SCHUNK + tid * 8;
    int v[8];
    int ts = 0;
#pragma unroll
    for (int i = 0; i < 8; ++i) {
        int idx = base + i;
        v[i] = (idx < n) ? cnt[idx] : 0;
        ts += v[i];
    }
    int incl = wave_incl_scan(ts);
    if (lane == 63) wtot[wid] = incl;
    __syncthreads();
    int woff = 0;
    for (int w = 0; w < wid; ++w) woff += wtot[w];
    int run = psum[blockIdx.x] + woff + incl - ts;   // exclusive base for this thread
#pragma unroll
    for (int i = 0; i < 8; ++i) {
        int idx = base + i;
        if (idx < n) { offs[idx] = run; cursor[idx] = run; }
        run += v[i];
    }
}

__global__ __launch_bounds__(256) void scatter_kernel(
        const int* __restrict__ rows, const int* __restrict__ cols,
        const float* __restrict__ vals, int* __restrict__ cursor,
        uint2* __restrict__ sorted, int E) {
    int i = blockIdx.x * blockDim.x + threadIdx.x;
    int stride = gridDim.x * blockDim.x;
    for (; i < E; i += stride) {
        int r = rows[i];
        int pos = atomicAdd(&cursor[r], 1);
        sorted[pos] = make_uint2((unsigned)cols[i], __float_as_uint(vals[i]));
    }
}

// ---------------- aggregation: one wave per node, 4 nodes/block ----------------
// 4-deep unrolled gather for memory-level parallelism; leaky fused; NT store.

__global__ __launch_bounds__(256) void agg_kernel(
        const float* __restrict__ h, const uint2* __restrict__ sorted,
        const int* __restrict__ offs, const int* __restrict__ cnt,
        float* __restrict__ out, int N) {
    const int node = blockIdx.x * 4 + ((int)threadIdx.x >> 6);
    if (node >= N) return;
    const int lane = (int)threadIdx.x & 63;
    const int beg = offs[node];
    const int end = beg + cnt[node];

    float4 acc0 = make_float4(0.f, 0.f, 0.f, 0.f);
    float4 acc1 = make_float4(0.f, 0.f, 0.f, 0.f);
    float4 acc2 = make_float4(0.f, 0.f, 0.f, 0.f);
    float4 acc3 = make_float4(0.f, 0.f, 0.f, 0.f);

    int j = beg;
    for (; j + 3 < end; j += 4) {
        uint2 cv0 = sorted[j];
        uint2 cv1 = sorted[j + 1];
        uint2 cv2 = sorted[j + 2];
        uint2 cv3 = sorted[j + 3];
        float4 h0 = *(const float4*)(&h[(size_t)cv0.x * DIM + lane * 4]);
        float4 h1 = *(const float4*)(&h[(size_t)cv1.x * DIM + lane * 4]);
        float4 h2 = *(const float4*)(&h[(size_t)cv2.x * DIM + lane * 4]);
        float4 h3 = *(const float4*)(&h[(size_t)cv3.x * DIM + lane * 4]);
        float v0 = __uint_as_float(cv0.y), v1 = __uint_as_float(cv1.y);
        float v2 = __uint_as_float(cv2.y), v3 = __uint_as_float(cv3.y);
        acc0.x += v0 * h0.x; acc0.y += v0 * h0.y; acc0.z += v0 * h0.z; acc0.w += v0 * h0.w;
        acc1.x += v1 * h1.x; acc1.y += v1 * h1.y; acc1.z += v1 * h1.z; acc1.w += v1 * h1.w;
        acc2.x += v2 * h2.x; acc2.y += v2 * h2.y; acc2.z += v2 * h2.z; acc2.w += v2 * h2.w;
        acc3.x += v3 * h3.x; acc3.y += v3 * h3.y; acc3.z += v3 * h3.z; acc3.w += v3 * h3.w;
    }
    for (; j < end; ++j) {
        uint2 cv = sorted[j];
        float v = __uint_as_float(cv.y);
        float4 hv = *(const float4*)(&h[(size_t)cv.x * DIM + lane * 4]);
        acc0.x += v * hv.x; acc0.y += v * hv.y; acc0.z += v * hv.z; acc0.w += v * hv.w;
    }
    vfloat4 a;
    a.x = acc0.x + acc1.x + acc2.x + acc3.x;
    a.y = acc0.y + acc1.y + acc2.y + acc3.y;
    a.z = acc0.z + acc1.z + acc2.z + acc3.z;
    a.w = acc0.w + acc1.w + acc2.w + acc3.w;
    a.x = (a.x >= 0.f) ? a.x : NEG_SLOPE * a.x;
    a.y = (a.y >= 0.f) ? a.y : NEG_SLOPE * a.y;
    a.z = (a.z >= 0.f) ? a.z : NEG_SLOPE * a.z;
    a.w = (a.w >= 0.f) ? a.w : NEG_SLOPE * a.w;
    __builtin_nontemporal_store(a, (vfloat4*)(&out[(size_t)node * DIM + lane * 4]));
}

// ---------------- fallback: atomic scatter (only if ws too small for CSR) ----------------

__global__ __launch_bounds__(64) void edge_atomic_kernel(
        const int* __restrict__ rows, const int* __restrict__ cols,
        const float* __restrict__ vals, const float* __restrict__ h,
        float* __restrict__ out, int E) {
    const int e = blockIdx.x;
    if (e >= E) return;
    const int lane = threadIdx.x;
    const int r = rows[e];
    const int c = cols[e];
    const float v = vals[e];
    float4 hv = *(const float4*)(&h[(size_t)c * DIM + lane * 4]);
    float* dst = &out[(size_t)r * DIM + lane * 4];
    atomicAdd(dst + 0, v * hv.x);
    atomicAdd(dst + 1, v * hv.y);
    atomicAdd(dst + 2, v * hv.z);
    atomicAdd(dst + 3, v * hv.w);
}

__global__ __launch_bounds__(256) void leaky_kernel(float* __restrict__ p, long long n) {
    long long i = (long long)blockIdx.x * blockDim.x + threadIdx.x;
    long long stride = (long long)gridDim.x * blockDim.x;
    for (; i < n; i += stride) {
        float v = p[i];
        p[i] = (v >= 0.f) ? v : NEG_SLOPE * v;
    }
}

// ---------------- launch ----------------

extern "C" void kernel_launch(void* const* d_in, const int* in_sizes, int n_in,
                              void* d_out, int out_size, void* d_ws, size_t ws_size,
                              hipStream_t stream) {
    const float* x    = (const float*)d_in[0];
    const int*   erow = (const int*)d_in[1];
    const int*   ecol = (const int*)d_in[2];
    const float* eval_ = (const float*)d_in[3];
    const float* Ww   = (const float*)d_in[4];
    const float* Wb   = (const float*)d_in[5];
    float* out = (float*)d_out;

    const int N = in_sizes[0] / DIM;
    const int E = in_sizes[1];
    const int nchunks = (N + SCHUNK - 1) / SCHUNK;

    // workspace layout
    char* p = (char*)d_ws;
    float* h = (float*)p;                       p += (size_t)N * DIM * sizeof(float);
    int* cnt = (int*)p;                         p += (size_t)N * sizeof(int);
    int* offs = (int*)p;                        p += (size_t)N * sizeof(int);
    int* cursor = (int*)p;                      p += (size_t)N * sizeof(int);
    int* psum = (int*)p;                        p += (size_t)((nchunks + 63) & ~63) * sizeof(int);
    uintptr_t up = ((uintptr_t)p + 15) & ~(uintptr_t)15;
    uint2* sorted = (uint2*)up;
    size_t need_full = (size_t)((char*)sorted - (char*)d_ws) + (size_t)E * sizeof(uint2);
    size_t need_h = (size_t)N * DIM * sizeof(float);

    // Phase 1: h = x @ W^T + b
    dim3 ggrid((N + GBM - 1) / GBM, DIM / GBN);
    gemm_xwT_kernel<<<ggrid, 256, 0, stream>>>(x, Ww, Wb, h, N);

    if (ws_size >= need_full) {
        // Phase 2: CSR build
        zero_i32_kernel<<<256, 256, 0, stream>>>(cnt, N);
        hist_kernel<<<1024, 256, 0, stream>>>(erow, cnt, E);
        chunk_sum_kernel<<<nchunks, 256, 0, stream>>>(cnt, psum, N);
        scan_psum_kernel<<<1, 64, 0, stream>>>(psum, nchunks);
        scan_final_kernel<<<nchunks, 256, 0, stream>>>(cnt, psum, offs, cursor, N);
        scatter_kernel<<<2048, 256, 0, stream>>>(erow, ecol, eval_, cursor, sorted, E);
        // Phase 3: per-node aggregation + fused leaky-relu
        agg_kernel<<<(N + 3) / 4, 256, 0, stream>>>(h, sorted, offs, cnt, out, N);
    } else if (ws_size >= need_h) {
        // fallback: atomic scatter
        zero_f32_kernel<<<2048, 256, 0, stream>>>(out, (long long)N * DIM);
        edge_atomic_kernel<<<E, 64, 0, stream>>>(erow, ecol, eval_, h, out, E);
        leaky_kernel<<<2048, 256, 0, stream>>>(out, (long long)N * DIM);
    }
}

// Round 4
// 787.098 us; speedup vs baseline: 1.3738x; 1.2345x over previous
//
#include <hip/hip_runtime.h>
#include <stdint.h>

#define DIM 256
#define NEG_SLOPE 0.01f

typedef float  vfloat4 __attribute__((ext_vector_type(4)));
typedef _Float16 vhalf4 __attribute__((ext_vector_type(4)));

// ---------------- utility kernels ----------------

__global__ __launch_bounds__(256) void zero_i32_kernel(int* __restrict__ p, int n) {
    int i = blockIdx.x * blockDim.x + threadIdx.x;
    int stride = gridDim.x * blockDim.x;
    for (; i < n; i += stride) p[i] = 0;
}

__global__ __launch_bounds__(256) void zero_f32_kernel(float* __restrict__ p, long long n) {
    long long i = (long long)blockIdx.x * blockDim.x + threadIdx.x;
    long long stride = (long long)gridDim.x * blockDim.x;
    for (; i < n; i += stride) p[i] = 0.0f;
}

// ---------------- GEMM: h = x @ W^T + b  (fp32 math, fp16 output) ----------------
// 128x64 tile per 256-thread block, BK=16, 8x4 micro-tile per thread.

#define GBM 128
#define GBN 64
#define GBK 16
#define GLDA 132
#define GLDB 68

__global__ __launch_bounds__(256) void gemm_xwT_kernel(
        const float* __restrict__ x, const float* __restrict__ W,
        const float* __restrict__ bias, _Float16* __restrict__ h, int M) {
    __shared__ float As[GBK][GLDA];   // As[k][r] = x[row0+r][kk+k]
    __shared__ float Bs[GBK][GLDB];   // Bs[k][c] = W[col0+c][kk+k]

    const int tid  = threadIdx.x;
    const int row0 = blockIdx.x * GBM;
    const int col0 = blockIdx.y * GBN;
    const int ty = tid >> 4;        // 0..15 -> output rows ty*8 .. ty*8+7
    const int tx = tid & 15;        // output cols tx*4 .. tx*4+3
    const int lr = tid >> 2;        // 0..63
    const int lk = (tid & 3) * 4;   // 0,4,8,12

    float acc[8][4];
#pragma unroll
    for (int i = 0; i < 8; ++i)
#pragma unroll
        for (int j = 0; j < 4; ++j) acc[i][j] = 0.0f;

    for (int kk = 0; kk < DIM; kk += GBK) {
#pragma unroll
        for (int i = 0; i < 2; ++i) {
            int row = row0 + lr + i * 64;
            float4 av = make_float4(0.f, 0.f, 0.f, 0.f);
            if (row < M)
                av = *(const float4*)(&x[(size_t)row * DIM + kk + lk]);
            As[lk + 0][lr + i * 64] = av.x; As[lk + 1][lr + i * 64] = av.y;
            As[lk + 2][lr + i * 64] = av.z; As[lk + 3][lr + i * 64] = av.w;
        }
        float4 bv = *(const float4*)(&W[(size_t)(col0 + lr) * DIM + kk + lk]);
        Bs[lk + 0][lr] = bv.x; Bs[lk + 1][lr] = bv.y;
        Bs[lk + 2][lr] = bv.z; Bs[lk + 3][lr] = bv.w;
        __syncthreads();

#pragma unroll
        for (int k = 0; k < GBK; ++k) {
            float4 a0 = *(const float4*)(&As[k][ty * 8]);
            float4 a1 = *(const float4*)(&As[k][ty * 8 + 4]);
            float4 b  = *(const float4*)(&Bs[k][tx * 4]);
            float ar[8] = {a0.x, a0.y, a0.z, a0.w, a1.x, a1.y, a1.z, a1.w};
            float br[4] = {b.x, b.y, b.z, b.w};
#pragma unroll
            for (int i = 0; i < 8; ++i)
#pragma unroll
                for (int j = 0; j < 4; ++j)
                    acc[i][j] += ar[i] * br[j];
        }
        __syncthreads();
    }

    const float4 bvec = *(const float4*)(&bias[col0 + tx * 4]);
#pragma unroll
    for (int i = 0; i < 8; ++i) {
        int row = row0 + ty * 8 + i;
        if (row < M) {
            vhalf4 o;
            o.x = (_Float16)(acc[i][0] + bvec.x);
            o.y = (_Float16)(acc[i][1] + bvec.y);
            o.z = (_Float16)(acc[i][2] + bvec.z);
            o.w = (_Float16)(acc[i][3] + bvec.w);
            *(vhalf4*)(&h[(size_t)row * DIM + col0 + tx * 4]) = o;
        }
    }
}

// ---------------- CSR build ----------------

__global__ __launch_bounds__(256) void hist_kernel(const int* __restrict__ rows,
                                                   int* __restrict__ cnt, int E) {
    int i = blockIdx.x * blockDim.x + threadIdx.x;
    int stride = gridDim.x * blockDim.x;
    for (; i < E; i += stride) atomicAdd(&cnt[rows[i]], 1);
}

__device__ inline int wave_incl_scan(int v) {
    const int lane = threadIdx.x & 63;
#pragma unroll
    for (int off = 1; off < 64; off <<= 1) {
        int t = __shfl_up(v, off, 64);
        if (lane >= off) v += t;
    }
    return v;
}

#define SCHUNK 2048   // 256 threads x 8 elements

__global__ __launch_bounds__(256) void chunk_sum_kernel(const int* __restrict__ cnt,
                                                        int* __restrict__ psum, int n) {
    __shared__ int wtot[4];
    const int tid = (int)threadIdx.x;
    const int lane = tid & 63, wid = tid >> 6;
    const int base = blockIdx.x * SCHUNK + tid * 8;
    int s = 0;
#pragma unroll
    for (int i = 0; i < 8; ++i) {
        int idx = base + i;
        if (idx < n) s += cnt[idx];
    }
#pragma unroll
    for (int off = 32; off; off >>= 1) s += __shfl_xor(s, off, 64);
    if (lane == 0) wtot[wid] = s;
    __syncthreads();
    if (tid == 0) psum[blockIdx.x] = wtot[0] + wtot[1] + wtot[2] + wtot[3];
}

__global__ __launch_bounds__(64) void scan_psum_kernel(int* __restrict__ psum, int nchunks) {
    const int lane = (int)threadIdx.x;
    int run = 0;
    for (int b = 0; b < nchunks; b += 64) {
        int i = b + lane;
        int v = (i < nchunks) ? psum[i] : 0;
        int incl = wave_incl_scan(v);
        if (i < nchunks) psum[i] = run + incl - v;  // exclusive
        run += __shfl(incl, 63, 64);
    }
}

__global__ __launch_bounds__(256) void scan_final_kernel(const int* __restrict__ cnt,
        const int* __restrict__ psum, int* __restrict__ offs,
        int* __restrict__ cursor, int n) {
    __shared__ int wtot[4];
    const int tid = (int)threadIdx.x;
    const int lane = tid & 63, wid = tid >> 6;
    const int base = blockIdx.x * SCHUNK + tid * 8;
    int v[8];
    int ts = 0;
#pragma unroll
    for (int i = 0; i < 8; ++i) {
        int idx = base + i;
        v[i] = (idx < n) ? cnt[idx] : 0;
        ts += v[i];
    }
    int incl = wave_incl_scan(ts);
    if (lane == 63) wtot[wid] = incl;
    __syncthreads();
    int woff = 0;
    for (int w = 0; w < wid; ++w) woff += wtot[w];
    int run = psum[blockIdx.x] + woff + incl - ts;
#pragma unroll
    for (int i = 0; i < 8; ++i) {
        int idx = base + i;
        if (idx < n) { offs[idx] = run; cursor[idx] = run; }
        run += v[i];
    }
}

__global__ __launch_bounds__(256) void scatter_kernel(
        const int* __restrict__ rows, const int* __restrict__ cols,
        const float* __restrict__ vals, int* __restrict__ cursor,
        uint2* __restrict__ sorted, int E) {
    int i = blockIdx.x * blockDim.x + threadIdx.x;
    int stride = gridDim.x * blockDim.x;
    for (; i < E; i += stride) {
        int r = rows[i];
        int pos = atomicAdd(&cursor[r], 1);
        sorted[pos] = make_uint2((unsigned)cols[i], __float_as_uint(vals[i]));
    }
}

// ---------------- aggregation: one wave per node, 4 nodes/block ----------------
// fp16 h gather (8B/lane/edge), 8-deep unroll, fp32 accumulate, fused leaky, NT store.

__global__ __launch_bounds__(256) void agg_kernel(
        const _Float16* __restrict__ h, const uint2* __restrict__ sorted,
        const int* __restrict__ offs, const int* __restrict__ cnt,
        float* __restrict__ out, int N) {
    const int node = blockIdx.x * 4 + ((int)threadIdx.x >> 6);
    if (node >= N) return;
    const int lane = (int)threadIdx.x & 63;
    const int beg = offs[node];
    const int end = beg + cnt[node];

    float4 acc0 = make_float4(0.f, 0.f, 0.f, 0.f);
    float4 acc1 = make_float4(0.f, 0.f, 0.f, 0.f);

    int j = beg;
    for (; j + 7 < end; j += 8) {
        uint2 cv[8];
        vhalf4 hv[8];
#pragma unroll
        for (int u = 0; u < 8; ++u) cv[u] = sorted[j + u];
#pragma unroll
        for (int u = 0; u < 8; ++u)
            hv[u] = *(const vhalf4*)(&h[(size_t)cv[u].x * DIM + lane * 4]);
#pragma unroll
        for (int u = 0; u < 8; ++u) {
            float v = __uint_as_float(cv[u].y);
            float4* a = (u & 1) ? &acc1 : &acc0;
            a->x += v * (float)hv[u].x;
            a->y += v * (float)hv[u].y;
            a->z += v * (float)hv[u].z;
            a->w += v * (float)hv[u].w;
        }
    }
    for (; j < end; ++j) {
        uint2 cv = sorted[j];
        float v = __uint_as_float(cv.y);
        vhalf4 hv = *(const vhalf4*)(&h[(size_t)cv.x * DIM + lane * 4]);
        acc0.x += v * (float)hv.x; acc0.y += v * (float)hv.y;
        acc0.z += v * (float)hv.z; acc0.w += v * (float)hv.w;
    }
    vfloat4 a;
    a.x = acc0.x + acc1.x;
    a.y = acc0.y + acc1.y;
    a.z = acc0.z + acc1.z;
    a.w = acc0.w + acc1.w;
    a.x = (a.x >= 0.f) ? a.x : NEG_SLOPE * a.x;
    a.y = (a.y >= 0.f) ? a.y : NEG_SLOPE * a.y;
    a.z = (a.z >= 0.f) ? a.z : NEG_SLOPE * a.z;
    a.w = (a.w >= 0.f) ? a.w : NEG_SLOPE * a.w;
    __builtin_nontemporal_store(a, (vfloat4*)(&out[(size_t)node * DIM + lane * 4]));
}

// ---------------- fallback: atomic scatter (only if ws too small for CSR) ----------------

__global__ __launch_bounds__(64) void edge_atomic_kernel(
        const int* __restrict__ rows, const int* __restrict__ cols,
        const float* __restrict__ vals, const _Float16* __restrict__ h,
        float* __restrict__ out, int E) {
    const int e = blockIdx.x;
    if (e >= E) return;
    const int lane = threadIdx.x;
    const int r = rows[e];
    const int c = cols[e];
    const float v = vals[e];
    vhalf4 hv = *(const vhalf4*)(&h[(size_t)c * DIM + lane * 4]);
    float* dst = &out[(size_t)r * DIM + lane * 4];
    atomicAdd(dst + 0, v * (float)hv.x);
    atomicAdd(dst + 1, v * (float)hv.y);
    atomicAdd(dst + 2, v * (float)hv.z);
    atomicAdd(dst + 3, v * (float)hv.w);
}

__global__ __launch_bounds__(256) void leaky_kernel(float* __restrict__ p, long long n) {
    long long i = (long long)blockIdx.x * blockDim.x + threadIdx.x;
    long long stride = (long long)gridDim.x * blockDim.x;
    for (; i < n; i += stride) {
        float v = p[i];
        p[i] = (v >= 0.f) ? v : NEG_SLOPE * v;
    }
}

// ---------------- launch ----------------

extern "C" void kernel_launch(void* const* d_in, const int* in_sizes, int n_in,
                              void* d_out, int out_size, void* d_ws, size_t ws_size,
                              hipStream_t stream) {
    const float* x    = (const float*)d_in[0];
    const int*   erow = (const int*)d_in[1];
    const int*   ecol = (const int*)d_in[2];
    const float* eval_ = (const float*)d_in[3];
    const float* Ww   = (const float*)d_in[4];
    const float* Wb   = (const float*)d_in[5];
    float* out = (float*)d_out;

    const int N = in_sizes[0] / DIM;
    const int E = in_sizes[1];
    const int nchunks = (N + SCHUNK - 1) / SCHUNK;

    // workspace layout
    char* p = (char*)d_ws;
    _Float16* h = (_Float16*)p;                 p += (size_t)N * DIM * sizeof(_Float16);
    int* cnt = (int*)p;                         p += (size_t)N * sizeof(int);
    int* offs = (int*)p;                        p += (size_t)N * sizeof(int);
    int* cursor = (int*)p;                      p += (size_t)N * sizeof(int);
    int* psum = (int*)p;                        p += (size_t)((nchunks + 63) & ~63) * sizeof(int);
    uintptr_t up = ((uintptr_t)p + 15) & ~(uintptr_t)15;
    uint2* sorted = (uint2*)up;
    size_t need_full = (size_t)((char*)sorted - (char*)d_ws) + (size_t)E * sizeof(uint2);
    size_t need_h = (size_t)N * DIM * sizeof(_Float16);

    // Phase 1: h = x @ W^T + b  (fp16 out)
    dim3 ggrid((N + GBM - 1) / GBM, DIM / GBN);
    gemm_xwT_kernel<<<ggrid, 256, 0, stream>>>(x, Ww, Wb, h, N);

    if (ws_size >= need_full) {
        // Phase 2: CSR build
        zero_i32_kernel<<<256, 256, 0, stream>>>(cnt, N);
        hist_kernel<<<1024, 256, 0, stream>>>(erow, cnt, E);
        chunk_sum_kernel<<<nchunks, 256, 0, stream>>>(cnt, psum, N);
        scan_psum_kernel<<<1, 64, 0, stream>>>(psum, nchunks);
        scan_final_kernel<<<nchunks, 256, 0, stream>>>(cnt, psum, offs, cursor, N);
        scatter_kernel<<<2048, 256, 0, stream>>>(erow, ecol, eval_, cursor, sorted, E);
        // Phase 3: per-node aggregation + fused leaky-relu
        agg_kernel<<<(N + 3) / 4, 256, 0, stream>>>(h, sorted, offs, cnt, out, N);
    } else if (ws_size >= need_h) {
        // fallback: atomic scatter
        zero_f32_kernel<<<2048, 256, 0, stream>>>(out, (long long)N * DIM);
        edge_atomic_kernel<<<E, 64, 0, stream>>>(erow, ecol, eval_, h, out, E);
        leaky_kernel<<<2048, 256, 0, stream>>>(out, (long long)N * DIM);
    }
}